// Round 6
// baseline (311.900 us; speedup 1.0000x reference)
//
#include <hip/hip_runtime.h>
#include <hip/hip_bf16.h>

#define D_MODEL 1024
#define N_HEADS 16
#define HEAD_DIM 64
#define BATCH 4
#define SEQ 2048
#define M_ROWS (BATCH * SEQ)  // 8192

typedef __attribute__((ext_vector_type(8))) __bf16 bf16x8;
typedef __attribute__((ext_vector_type(8))) short short8;
typedef __attribute__((ext_vector_type(4))) float f32x4;

static __device__ __forceinline__ unsigned short f2bf_rne(float f) {
  unsigned int u = __float_as_uint(f);
  u += 0x7FFFu + ((u >> 16) & 1u);
  return (unsigned short)(u >> 16);
}

// 2^x via compiler-visible intrinsic (hazard recognizer inserts the MFMA->VALU and
// trans-use wait states; the round-5 raw inline-asm version read a stale VGPR).
#if __has_builtin(__builtin_amdgcn_exp2f)
#define EXP2F(x) __builtin_amdgcn_exp2f(x)
#else
#define EXP2F(x) exp2f(x)
#endif

static __device__ __forceinline__ void gl_lds16(const unsigned short* g, unsigned short* l) {
  __builtin_amdgcn_global_load_lds((const __attribute__((address_space(1))) unsigned int*)g,
                                   (__attribute__((address_space(3))) unsigned int*)l, 16, 0, 0);
}

// ---------------- merged fp32 -> bf16 conversion (x + 4 weights), one launch ----------------
__global__ __launch_bounds__(256) void cvt_all(const float* __restrict__ x,
                                               const float* __restrict__ wq,
                                               const float* __restrict__ wk,
                                               const float* __restrict__ wv,
                                               const float* __restrict__ wo,
                                               unsigned short* __restrict__ xb,
                                               unsigned short* __restrict__ wqb,
                                               unsigned short* __restrict__ wkb,
                                               unsigned short* __restrict__ wvb,
                                               unsigned short* __restrict__ wob) {
  const int bid = blockIdx.x;
  const float* src;
  unsigned short* dst;
  int i;
  if (bid < 8192) {
    src = x; dst = xb; i = bid * 256 + threadIdx.x;
  } else {
    int r = bid - 8192;
    int w = r >> 10;
    i = (r & 1023) * 256 + threadIdx.x;
    switch (w) {
      case 0: src = wq; dst = wqb; break;
      case 1: src = wk; dst = wkb; break;
      case 2: src = wv; dst = wvb; break;
      default: src = wo; dst = wob; break;
    }
  }
  float4 f = reinterpret_cast<const float4*>(src)[i];
  ushort4 o;
  o.x = f2bf_rne(f.x); o.y = f2bf_rne(f.y); o.z = f2bf_rne(f.z); o.w = f2bf_rne(f.w);
  reinterpret_cast<ushort4*>(dst)[i] = o;
}

// ---------------- fused QKV GEMM ----------------
// grid (24, 64): bn 0..7 -> Q (scale log2e/8), 8..15 -> K, 16..23 -> V (written TRANSPOSED
// into Vt[(b*16+h)*64+d][s] via LDS). m97-style global_load_lds staging.
__global__ __launch_bounds__(256) void qkv_gemm(const unsigned short* __restrict__ A,
                                                const unsigned short* __restrict__ Wq,
                                                const unsigned short* __restrict__ Wk,
                                                const unsigned short* __restrict__ Wv,
                                                unsigned short* __restrict__ Qo,
                                                unsigned short* __restrict__ Ko,
                                                unsigned short* __restrict__ Vt) {
  __shared__ __align__(16) unsigned short smem[64 * 136];  // As[0:4096] Bs[4096:8192]; T reuse
  unsigned short* As = smem;
  unsigned short* Bs = smem + 4096;

  const int t = threadIdx.x;
  const int widx = blockIdx.x >> 3;
  const int bn = blockIdx.x & 7, bm = blockIdx.y;
  const unsigned short* Bw = (widx == 0) ? Wq : (widx == 1) ? Wk : Wv;
  const float oscale = (widx == 0) ? 0.18033688f : 1.0f;  // Q: 1/8 * log2(e)
  const int K = D_MODEL, N = D_MODEL;

  const int wave = t >> 6, lane = t & 63;
  const int wm = (wave >> 1) * 64, wn = (wave & 1) * 64;
  const int lr = lane & 15, quad = lane >> 4;

  f32x4 acc[4][4] = {};

  for (int k0 = 0; k0 < K; k0 += 32) {
    __syncthreads();
#pragma unroll
    for (int i = 0; i < 2; i++) {
      int g = wave * 128 + i * 64 + lane;
      int row = g >> 2, col8 = (g & 3) << 3;
      gl_lds16(A + (size_t)(bm * 128 + row) * K + k0 + col8, &As[g * 8]);
      gl_lds16(Bw + (size_t)(bn * 128 + row) * K + k0 + col8, &Bs[g * 8]);
    }
    __syncthreads();

    bf16x8 af[4], bfr[4];
#pragma unroll
    for (int mt = 0; mt < 4; mt++)
      af[mt] = __builtin_bit_cast(
          bf16x8, *reinterpret_cast<const short8*>(&As[(wm + mt * 16 + lr) * 32 + quad * 8]));
#pragma unroll
    for (int nt = 0; nt < 4; nt++)
      bfr[nt] = __builtin_bit_cast(
          bf16x8, *reinterpret_cast<const short8*>(&Bs[(wn + nt * 16 + lr) * 32 + quad * 8]));
#pragma unroll
    for (int mt = 0; mt < 4; mt++)
#pragma unroll
      for (int nt = 0; nt < 4; nt++)
        acc[mt][nt] = __builtin_amdgcn_mfma_f32_16x16x32_bf16(af[mt], bfr[nt], acc[mt][nt], 0, 0, 0);
  }

  if (widx < 2) {
    unsigned short* Cp = (widx == 0) ? Qo : Ko;
#pragma unroll
    for (int mt = 0; mt < 4; mt++) {
#pragma unroll
      for (int nt = 0; nt < 4; nt++) {
        int col = bn * 128 + wn + nt * 16 + lr;
#pragma unroll
        for (int r = 0; r < 4; r++) {
          int row = bm * 128 + wm + mt * 16 + quad * 4 + r;
          Cp[(size_t)row * N + col] = f2bf_rne(acc[mt][nt][r] * oscale);
        }
      }
    }
  } else {
    // V: transpose through LDS, write Vt[(b*16+h2)*64+d][bm*128%2048 + s]
    const int b = bm >> 4;
    const int s0 = (bm & 15) * 128;
#pragma unroll
    for (int half = 0; half < 2; half++) {
      __syncthreads();  // k-loop LDS reads (or prev half's T reads) complete
      if ((wave & 1) == half) {
#pragma unroll
        for (int nt = 0; nt < 4; nt++) {
#pragma unroll
          for (int mt = 0; mt < 4; mt++) {
#pragma unroll
            for (int r = 0; r < 4; r++) {
              int cl = nt * 16 + lr;                    // d within this 64-col half
              int rl = wm + mt * 16 + quad * 4 + r;     // s within 128-row tile
              smem[cl * 136 + rl] = f2bf_rne(acc[mt][nt][r]);
            }
          }
        }
      }
      __syncthreads();
      const int h2 = bn * 2 + half;
      const size_t rowbase = ((size_t)(b * N_HEADS + h2)) * HEAD_DIM;
#pragma unroll
      for (int i = 0; i < 4; i++) {
        int c = i * 256 + t;
        int d = c >> 4, s8 = (c & 15) * 8;
        uint4 v = *reinterpret_cast<const uint4*>(&smem[d * 136 + s8]);
        *reinterpret_cast<uint4*>(Vt + (rowbase + d) * SEQ + s0 + s8) = v;
      }
    }
  }
}

// ---------------- O-projection GEMM: out[M,N] = Ob[M,K] * Wo[N,K]^T, f32 out ----------------
__global__ __launch_bounds__(256) void gemm_bt_f32(const unsigned short* __restrict__ A,
                                                   const unsigned short* __restrict__ Bw,
                                                   float* __restrict__ Cp,
                                                   int M, int N, int K) {
  __shared__ __align__(16) unsigned short As[128 * 32];
  __shared__ __align__(16) unsigned short Bs[128 * 32];
  const int t = threadIdx.x;
  const int bn = blockIdx.x, bm = blockIdx.y;
  const int wave = t >> 6, lane = t & 63;
  const int wm = (wave >> 1) * 64, wn = (wave & 1) * 64;
  const int lr = lane & 15, quad = lane >> 4;

  f32x4 acc[4][4] = {};

  for (int k0 = 0; k0 < K; k0 += 32) {
    __syncthreads();
#pragma unroll
    for (int i = 0; i < 2; i++) {
      int g = wave * 128 + i * 64 + lane;
      int row = g >> 2, col8 = (g & 3) << 3;
      gl_lds16(A + (size_t)(bm * 128 + row) * K + k0 + col8, &As[g * 8]);
      gl_lds16(Bw + (size_t)(bn * 128 + row) * K + k0 + col8, &Bs[g * 8]);
    }
    __syncthreads();

    bf16x8 af[4], bfr[4];
#pragma unroll
    for (int mt = 0; mt < 4; mt++)
      af[mt] = __builtin_bit_cast(
          bf16x8, *reinterpret_cast<const short8*>(&As[(wm + mt * 16 + lr) * 32 + quad * 8]));
#pragma unroll
    for (int nt = 0; nt < 4; nt++)
      bfr[nt] = __builtin_bit_cast(
          bf16x8, *reinterpret_cast<const short8*>(&Bs[(wn + nt * 16 + lr) * 32 + quad * 8]));
#pragma unroll
    for (int mt = 0; mt < 4; mt++)
#pragma unroll
      for (int nt = 0; nt < 4; nt++)
        acc[mt][nt] = __builtin_amdgcn_mfma_f32_16x16x32_bf16(af[mt], bfr[nt], acc[mt][nt], 0, 0, 0);
  }

#pragma unroll
  for (int mt = 0; mt < 4; mt++) {
#pragma unroll
    for (int nt = 0; nt < 4; nt++) {
      int col = bn * 128 + wn + nt * 16 + lr;
#pragma unroll
      for (int r = 0; r < 4; r++) {
        int row = bm * 128 + wm + mt * 16 + quad * 4 + r;
        Cp[(size_t)row * N + col] = acc[mt][nt][r];
      }
    }
  }
}

// ---------------- causal flash attention v5: balanced + XCD-local ----------------
// 1024 blocks; bid = p*64 + (b*16+h) so all 16 p-blocks of one (b,h) share bid%8 -> same
// XCD L2 caches that (b,h)'s K+Vt (512 KB; 8 pairs = 4 MB/XCD). Block = paired q-tiles
// {p, 31-p} (64 rows each, two phases) -> exactly 33 kv-tiles per block. 4 waves x 16 rows.
// Fixed-max softmax in base-2 (Q pre-scaled by log2(e)/8); native exp2 intrinsic.
__global__ __launch_bounds__(256, 4) void attn_causal(const unsigned short* __restrict__ Q,
                                                      const unsigned short* __restrict__ Km,
                                                      const unsigned short* __restrict__ Vt,
                                                      unsigned short* __restrict__ O) {
  __shared__ __align__(16) unsigned short Ks[64 * 72];
  __shared__ __align__(16) unsigned short Vs[64 * 72];
  __shared__ __align__(16) unsigned short Ps[4][16 * 72];

  const int bid = blockIdx.x;
  const int p = bid >> 6;    // 0..15
  const int bh = bid & 63;   // XCD selector: bid%8 == bh%8
  const int h = bh & 15;
  const int b = bh >> 4;

  const int t = threadIdx.x;
  const int wave = t >> 6, lane = t & 63;
  const int lr = lane & 15, quad = lane >> 4;

  const size_t base = (size_t)b * SEQ * D_MODEL + h * HEAD_DIM;
  const unsigned short* Qb = Q + base;
  const unsigned short* Kb = Km + base;
  const unsigned short* Vb = Vt + (size_t)(b * N_HEADS + h) * HEAD_DIM * SEQ;
  unsigned short* pw = &Ps[wave][0];

  const int sr = t >> 3, sc = (t & 7) << 3;  // staging: rows sr, sr+32, col sc (8 shorts)

  for (int ph = 0; ph < 2; ph++) {
    const int qt = ph ? (31 - p) : p;
    const int m0 = qt * 64 + wave * 16;
    const int ntiles = qt + 1;

    bf16x8 qf[2];
#pragma unroll
    for (int kk = 0; kk < 2; kk++)
      qf[kk] = __builtin_bit_cast(
          bf16x8,
          *reinterpret_cast<const short8*>(Qb + (size_t)(m0 + lr) * D_MODEL + kk * 32 + quad * 8));

    f32x4 o_acc[4] = {};
    float lsum[4] = {};

    uint4 ra = *reinterpret_cast<const uint4*>(Kb + (size_t)sr * D_MODEL + sc);
    uint4 rb = *reinterpret_cast<const uint4*>(Kb + (size_t)(sr + 32) * D_MODEL + sc);
    uint4 rc = *reinterpret_cast<const uint4*>(Vb + (size_t)sr * SEQ + sc);
    uint4 rd = *reinterpret_cast<const uint4*>(Vb + (size_t)(sr + 32) * SEQ + sc);

    for (int kt = 0; kt < ntiles; kt++) {
      const int kv0 = kt * 64;
      __syncthreads();  // all waves done reading prior tile (and prior phase)
      *reinterpret_cast<uint4*>(&Ks[sr * 72 + sc]) = ra;
      *reinterpret_cast<uint4*>(&Ks[(sr + 32) * 72 + sc]) = rb;
      *reinterpret_cast<uint4*>(&Vs[sr * 72 + sc]) = rc;
      *reinterpret_cast<uint4*>(&Vs[(sr + 32) * 72 + sc]) = rd;
      __syncthreads();
      if (kt + 1 < ntiles) {  // prefetch next tile (overlaps compute)
        const int kv1 = kv0 + 64;
        ra = *reinterpret_cast<const uint4*>(Kb + (size_t)(kv1 + sr) * D_MODEL + sc);
        rb = *reinterpret_cast<const uint4*>(Kb + (size_t)(kv1 + sr + 32) * D_MODEL + sc);
        rc = *reinterpret_cast<const uint4*>(Vb + (size_t)sr * SEQ + kv1 + sc);
        rd = *reinterpret_cast<const uint4*>(Vb + (size_t)(sr + 32) * SEQ + kv1 + sc);
      }

      // ---- QK^T over 64 kv cols ----
      f32x4 sAcc[4] = {};
#pragma unroll
      for (int kk = 0; kk < 2; kk++) {
        bf16x8 kf[4];
#pragma unroll
        for (int j = 0; j < 4; j++)
          kf[j] = __builtin_bit_cast(
              bf16x8, *reinterpret_cast<const short8*>(&Ks[(j * 16 + lr) * 72 + kk * 32 + quad * 8]));
#pragma unroll
        for (int j = 0; j < 4; j++)
          sAcc[j] = __builtin_amdgcn_mfma_f32_16x16x32_bf16(qf[kk], kf[j], sAcc[j], 0, 0, 0);
      }

      asm volatile("s_waitcnt lgkmcnt(0)" ::: "memory");  // prev P-frag reads drained
#pragma unroll
      for (int r = 0; r < 4; r++) {
        const int qpos = m0 + quad * 4 + r;
        float e[4];
#pragma unroll
        for (int j = 0; j < 4; j++) e[j] = EXP2F(sAcc[j][r]);
        if (kt == ntiles - 1) {
#pragma unroll
          for (int j = 0; j < 4; j++)
            if (kv0 + j * 16 + lr > qpos) e[j] = 0.f;
        }
        lsum[r] += (e[0] + e[1]) + (e[2] + e[3]);
        unsigned short* pr = &pw[(quad * 4 + r) * 72];
#pragma unroll
        for (int j = 0; j < 4; j++) pr[j * 16 + lr] = f2bf_rne(e[j]);
      }
      asm volatile("s_waitcnt lgkmcnt(0)" ::: "memory");  // P writes visible (wave-lockstep)

      // ---- PV ----
#pragma unroll
      for (int kk = 0; kk < 2; kk++) {
        bf16x8 pf = __builtin_bit_cast(
            bf16x8, *reinterpret_cast<const short8*>(&pw[lr * 72 + kk * 32 + quad * 8]));
#pragma unroll
        for (int c = 0; c < 4; c++) {
          bf16x8 vv = __builtin_bit_cast(
              bf16x8, *reinterpret_cast<const short8*>(&Vs[(c * 16 + lr) * 72 + kk * 32 + quad * 8]));
          o_acc[c] = __builtin_amdgcn_mfma_f32_16x16x32_bf16(pf, vv, o_acc[c], 0, 0, 0);
        }
      }
    }

    // epilogue
#pragma unroll
    for (int r = 0; r < 4; r++) {
      float l = lsum[r];
#pragma unroll
      for (int off = 1; off < 16; off <<= 1) l += __shfl_xor(l, off, 64);
      const float inv = 1.f / l;
      const int qpos = m0 + quad * 4 + r;
#pragma unroll
      for (int c = 0; c < 4; c++)
        O[base + (size_t)qpos * D_MODEL + c * 16 + lr] = f2bf_rne(o_acc[c][r] * inv);
    }
  }
}

// ---------------- launch ----------------
extern "C" void kernel_launch(void* const* d_in, const int* in_sizes, int n_in,
                              void* d_out, int out_size, void* d_ws, size_t ws_size,
                              hipStream_t stream) {
  const float* x  = (const float*)d_in[0];
  const float* Wq = (const float*)d_in[1];
  const float* Wk = (const float*)d_in[2];
  const float* Wv = (const float*)d_in[3];
  const float* Wo = (const float*)d_in[4];
  float* out = (float*)d_out;

  char* ws = (char*)d_ws;
  const size_t SZ_X = (size_t)M_ROWS * D_MODEL * 2;   // 16 MB
  const size_t SZ_W = (size_t)D_MODEL * D_MODEL * 2;  //  2 MB
  unsigned short* xb  = (unsigned short*)(ws);
  unsigned short* wqb = (unsigned short*)(ws + SZ_X);
  unsigned short* wkb = (unsigned short*)(ws + SZ_X + 1 * SZ_W);
  unsigned short* wvb = (unsigned short*)(ws + SZ_X + 2 * SZ_W);
  unsigned short* wob = (unsigned short*)(ws + SZ_X + 3 * SZ_W);
  unsigned short* Qb  = (unsigned short*)(ws + 1 * SZ_X + 4 * SZ_W);
  unsigned short* Kb  = (unsigned short*)(ws + 2 * SZ_X + 4 * SZ_W);
  unsigned short* Vt  = (unsigned short*)(ws + 3 * SZ_X + 4 * SZ_W);
  unsigned short* Ob  = xb;  // x dead after QKV projection

  cvt_all<<<12288, 256, 0, stream>>>(x, Wq, Wk, Wv, Wo, xb, wqb, wkb, wvb, wob);

  qkv_gemm<<<dim3(24, 64), 256, 0, stream>>>(xb, wqb, wkb, wvb, Qb, Kb, Vt);

  attn_causal<<<1024, 256, 0, stream>>>(Qb, Kb, Vt, Ob);

  gemm_bt_f32<<<dim3(8, 64), 256, 0, stream>>>(Ob, wob, out, M_ROWS, D_MODEL, D_MODEL);
}

// Round 7
// 276.466 us; speedup vs baseline: 1.1282x; 1.1282x over previous
//
#include <hip/hip_runtime.h>
#include <hip/hip_bf16.h>

#define D_MODEL 1024
#define N_HEADS 16
#define HEAD_DIM 64
#define BATCH 4
#define SEQ 2048
#define M_ROWS (BATCH * SEQ)  // 8192

typedef __attribute__((ext_vector_type(8))) __bf16 bf16x8;
typedef __attribute__((ext_vector_type(8))) short short8;
typedef __attribute__((ext_vector_type(4))) float f32x4;

static __device__ __forceinline__ unsigned short f2bf_rne(float f) {
  unsigned int u = __float_as_uint(f);
  u += 0x7FFFu + ((u >> 16) & 1u);
  return (unsigned short)(u >> 16);
}

#if __has_builtin(__builtin_amdgcn_exp2f)
#define EXP2F(x) __builtin_amdgcn_exp2f(x)
#else
#define EXP2F(x) exp2f(x)
#endif

static __device__ __forceinline__ void gl_lds16(const unsigned short* g, unsigned short* l) {
  __builtin_amdgcn_global_load_lds((const __attribute__((address_space(1))) unsigned int*)g,
                                   (__attribute__((address_space(3))) unsigned int*)l, 16, 0, 0);
}

// ---------------- merged fp32 -> bf16 conversion (x + 4 weights), one launch ----------------
__global__ __launch_bounds__(256) void cvt_all(const float* __restrict__ x,
                                               const float* __restrict__ wq,
                                               const float* __restrict__ wk,
                                               const float* __restrict__ wv,
                                               const float* __restrict__ wo,
                                               unsigned short* __restrict__ xb,
                                               unsigned short* __restrict__ wqb,
                                               unsigned short* __restrict__ wkb,
                                               unsigned short* __restrict__ wvb,
                                               unsigned short* __restrict__ wob) {
  const int bid = blockIdx.x;
  const float* src;
  unsigned short* dst;
  int i;
  if (bid < 8192) {
    src = x; dst = xb; i = bid * 256 + threadIdx.x;
  } else {
    int r = bid - 8192;
    int w = r >> 10;
    i = (r & 1023) * 256 + threadIdx.x;
    switch (w) {
      case 0: src = wq; dst = wqb; break;
      case 1: src = wk; dst = wkb; break;
      case 2: src = wv; dst = wvb; break;
      default: src = wo; dst = wob; break;
    }
  }
  float4 f = reinterpret_cast<const float4*>(src)[i];
  ushort4 o;
  o.x = f2bf_rne(f.x); o.y = f2bf_rne(f.y); o.z = f2bf_rne(f.z); o.w = f2bf_rne(f.w);
  reinterpret_cast<ushort4*>(dst)[i] = o;
}

// ---------------- fused QKV GEMM, double-buffered LDS ----------------
// grid (24, 64): bn 0..7 -> Q (scale log2e/8), 8..15 -> K, 16..23 -> V (written TRANSPOSED
// into Vt[(b*16+h)*64+d][s] via LDS). Ping-pong staging: loads for tile k+1 issued right
// after the barrier, vmcnt drain at iter end comes a full compute phase later.
__global__ __launch_bounds__(256) void qkv_gemm(const unsigned short* __restrict__ A,
                                                const unsigned short* __restrict__ Wq,
                                                const unsigned short* __restrict__ Wk,
                                                const unsigned short* __restrict__ Wv,
                                                unsigned short* __restrict__ Qo,
                                                unsigned short* __restrict__ Ko,
                                                unsigned short* __restrict__ Vt) {
  __shared__ __align__(16) unsigned short smem[16384];  // As0 Bs0 As1 Bs1, 4096 shorts each
  const int t = threadIdx.x;
  const int widx = blockIdx.x >> 3;
  const int bn = blockIdx.x & 7, bm = blockIdx.y;
  const unsigned short* Bw = (widx == 0) ? Wq : (widx == 1) ? Wk : Wv;
  const float oscale = (widx == 0) ? 0.18033688f : 1.0f;  // Q: 1/8 * log2(e)
  const int K = D_MODEL, N = D_MODEL;

  const int wave = t >> 6, lane = t & 63;
  const int wm = (wave >> 1) * 64, wn = (wave & 1) * 64;
  const int lr = lane & 15, quad = lane >> 4;

  // staging addresses for this thread (2 granules per tile per operand)
  const int g0 = wave * 128 + lane, g1 = g0 + 64;
  const int r0 = g0 >> 2, c0 = (g0 & 3) << 3;
  const int r1 = g1 >> 2, c1 = (g1 & 3) << 3;
  const unsigned short* Arow0 = A + (size_t)(bm * 128 + r0) * K + c0;
  const unsigned short* Arow1 = A + (size_t)(bm * 128 + r1) * K + c1;
  const unsigned short* Brow0 = Bw + (size_t)(bn * 128 + r0) * K + c0;
  const unsigned short* Brow1 = Bw + (size_t)(bn * 128 + r1) * K + c1;

  f32x4 acc[4][4] = {};

  // prologue: stage tile 0 into buffer 0
  gl_lds16(Arow0, &smem[g0 * 8]);
  gl_lds16(Arow1, &smem[g1 * 8]);
  gl_lds16(Brow0, &smem[4096 + g0 * 8]);
  gl_lds16(Brow1, &smem[4096 + g1 * 8]);
  __syncthreads();

  for (int it = 0; it < 32; it++) {
    const int cur = (it & 1) * 8192;
    if (it + 1 < 32) {  // stage next tile into the other buffer (drained at iter-end barrier)
      const int nxt = 8192 - cur;
      const int k1 = (it + 1) * 32;
      gl_lds16(Arow0 + k1, &smem[nxt + g0 * 8]);
      gl_lds16(Arow1 + k1, &smem[nxt + g1 * 8]);
      gl_lds16(Brow0 + k1, &smem[nxt + 4096 + g0 * 8]);
      gl_lds16(Brow1 + k1, &smem[nxt + 4096 + g1 * 8]);
    }
    const unsigned short* As = &smem[cur];
    const unsigned short* Bs = &smem[cur + 4096];

    bf16x8 af[4], bfr[4];
#pragma unroll
    for (int mt = 0; mt < 4; mt++)
      af[mt] = __builtin_bit_cast(
          bf16x8, *reinterpret_cast<const short8*>(&As[(wm + mt * 16 + lr) * 32 + quad * 8]));
#pragma unroll
    for (int nt = 0; nt < 4; nt++)
      bfr[nt] = __builtin_bit_cast(
          bf16x8, *reinterpret_cast<const short8*>(&Bs[(wn + nt * 16 + lr) * 32 + quad * 8]));
#pragma unroll
    for (int mt = 0; mt < 4; mt++)
#pragma unroll
      for (int nt = 0; nt < 4; nt++)
        acc[mt][nt] = __builtin_amdgcn_mfma_f32_16x16x32_bf16(af[mt], bfr[nt], acc[mt][nt], 0, 0, 0);
    __syncthreads();
  }

  if (widx < 2) {
    unsigned short* Cp = (widx == 0) ? Qo : Ko;
#pragma unroll
    for (int mt = 0; mt < 4; mt++) {
#pragma unroll
      for (int nt = 0; nt < 4; nt++) {
        int col = bn * 128 + wn + nt * 16 + lr;
#pragma unroll
        for (int r = 0; r < 4; r++) {
          int row = bm * 128 + wm + mt * 16 + quad * 4 + r;
          Cp[(size_t)row * N + col] = f2bf_rne(acc[mt][nt][r] * oscale);
        }
      }
    }
  } else {
    // V: transpose through LDS (reuses smem), write Vt[(b*16+h2)*64+d][s]
    const int b = bm >> 4;
    const int s0 = (bm & 15) * 128;
#pragma unroll
    for (int half = 0; half < 2; half++) {
      __syncthreads();
      if ((wave & 1) == half) {
#pragma unroll
        for (int nt = 0; nt < 4; nt++) {
#pragma unroll
          for (int mt = 0; mt < 4; mt++) {
#pragma unroll
            for (int r = 0; r < 4; r++) {
              int cl = nt * 16 + lr;                 // d within this 64-col half
              int rl = wm + mt * 16 + quad * 4 + r;  // s within 128-row tile
              smem[cl * 136 + rl] = f2bf_rne(acc[mt][nt][r]);
            }
          }
        }
      }
      __syncthreads();
      const int h2 = bn * 2 + half;
      const size_t rowbase = ((size_t)(b * N_HEADS + h2)) * HEAD_DIM;
#pragma unroll
      for (int i = 0; i < 4; i++) {
        int c = i * 256 + t;
        int d = c >> 4, s8 = (c & 15) * 8;
        uint4 v = *reinterpret_cast<const uint4*>(&smem[d * 136 + s8]);
        *reinterpret_cast<uint4*>(Vt + (rowbase + d) * SEQ + s0 + s8) = v;
      }
    }
  }
}

// ---------------- O-projection GEMM, double-buffered: out = Ob * Wo^T, f32 out ----------------
__global__ __launch_bounds__(256) void gemm_bt_f32(const unsigned short* __restrict__ A,
                                                   const unsigned short* __restrict__ Bw,
                                                   float* __restrict__ Cp,
                                                   int M, int N, int K) {
  __shared__ __align__(16) unsigned short smem[16384];
  const int t = threadIdx.x;
  const int bn = blockIdx.x, bm = blockIdx.y;
  const int wave = t >> 6, lane = t & 63;
  const int wm = (wave >> 1) * 64, wn = (wave & 1) * 64;
  const int lr = lane & 15, quad = lane >> 4;

  const int g0 = wave * 128 + lane, g1 = g0 + 64;
  const int r0 = g0 >> 2, c0 = (g0 & 3) << 3;
  const int r1 = g1 >> 2, c1 = (g1 & 3) << 3;
  const unsigned short* Arow0 = A + (size_t)(bm * 128 + r0) * K + c0;
  const unsigned short* Arow1 = A + (size_t)(bm * 128 + r1) * K + c1;
  const unsigned short* Brow0 = Bw + (size_t)(bn * 128 + r0) * K + c0;
  const unsigned short* Brow1 = Bw + (size_t)(bn * 128 + r1) * K + c1;

  f32x4 acc[4][4] = {};

  gl_lds16(Arow0, &smem[g0 * 8]);
  gl_lds16(Arow1, &smem[g1 * 8]);
  gl_lds16(Brow0, &smem[4096 + g0 * 8]);
  gl_lds16(Brow1, &smem[4096 + g1 * 8]);
  __syncthreads();

  const int niter = K / 32;
  for (int it = 0; it < niter; it++) {
    const int cur = (it & 1) * 8192;
    if (it + 1 < niter) {
      const int nxt = 8192 - cur;
      const int k1 = (it + 1) * 32;
      gl_lds16(Arow0 + k1, &smem[nxt + g0 * 8]);
      gl_lds16(Arow1 + k1, &smem[nxt + g1 * 8]);
      gl_lds16(Brow0 + k1, &smem[nxt + 4096 + g0 * 8]);
      gl_lds16(Brow1 + k1, &smem[nxt + 4096 + g1 * 8]);
    }
    const unsigned short* As = &smem[cur];
    const unsigned short* Bs = &smem[cur + 4096];

    bf16x8 af[4], bfr[4];
#pragma unroll
    for (int mt = 0; mt < 4; mt++)
      af[mt] = __builtin_bit_cast(
          bf16x8, *reinterpret_cast<const short8*>(&As[(wm + mt * 16 + lr) * 32 + quad * 8]));
#pragma unroll
    for (int nt = 0; nt < 4; nt++)
      bfr[nt] = __builtin_bit_cast(
          bf16x8, *reinterpret_cast<const short8*>(&Bs[(wn + nt * 16 + lr) * 32 + quad * 8]));
#pragma unroll
    for (int mt = 0; mt < 4; mt++)
#pragma unroll
      for (int nt = 0; nt < 4; nt++)
        acc[mt][nt] = __builtin_amdgcn_mfma_f32_16x16x32_bf16(af[mt], bfr[nt], acc[mt][nt], 0, 0, 0);
    __syncthreads();
  }

#pragma unroll
  for (int mt = 0; mt < 4; mt++) {
#pragma unroll
    for (int nt = 0; nt < 4; nt++) {
      int col = bn * 128 + wn + nt * 16 + lr;
#pragma unroll
      for (int r = 0; r < 4; r++) {
        int row = bm * 128 + wm + mt * 16 + quad * 4 + r;
        Cp[(size_t)row * N + col] = acc[mt][nt][r];
      }
    }
  }
}

// ---------------- causal flash attention: balanced paired q-tiles (round-4 mapping) ----------------
// 1024 blocks, (b,h,p): p = bid&15 -> q-tiles {p, 31-p} (64 rows each), two phases ->
// exactly 33 kv-tiles per block. 4 waves x 16 q rows. KV tiles of 64 staged block-
// cooperatively; register prefetch. Fixed-max softmax base-2 (Q pre-scaled by log2(e)/8).
__global__ __launch_bounds__(256, 4) void attn_causal(const unsigned short* __restrict__ Q,
                                                      const unsigned short* __restrict__ Km,
                                                      const unsigned short* __restrict__ Vt,
                                                      unsigned short* __restrict__ O) {
  __shared__ __align__(16) unsigned short Ks[64 * 72];
  __shared__ __align__(16) unsigned short Vs[64 * 72];
  __shared__ __align__(16) unsigned short Ps[4][16 * 72];

  const int bid = blockIdx.x;
  const int p = bid & 15;
  const int h = (bid >> 4) & 15;
  const int b = bid >> 8;

  const int t = threadIdx.x;
  const int wave = t >> 6, lane = t & 63;
  const int lr = lane & 15, quad = lane >> 4;

  const size_t base = (size_t)b * SEQ * D_MODEL + h * HEAD_DIM;
  const unsigned short* Qb = Q + base;
  const unsigned short* Kb = Km + base;
  const unsigned short* Vb = Vt + (size_t)(b * N_HEADS + h) * HEAD_DIM * SEQ;
  unsigned short* pw = &Ps[wave][0];

  const int sr = t >> 3, sc = (t & 7) << 3;  // staging: rows sr, sr+32, col sc (8 shorts)

  for (int ph = 0; ph < 2; ph++) {
    const int qt = ph ? (31 - p) : p;
    const int m0 = qt * 64 + wave * 16;
    const int ntiles = qt + 1;

    bf16x8 qf[2];
#pragma unroll
    for (int kk = 0; kk < 2; kk++)
      qf[kk] = __builtin_bit_cast(
          bf16x8,
          *reinterpret_cast<const short8*>(Qb + (size_t)(m0 + lr) * D_MODEL + kk * 32 + quad * 8));

    f32x4 o_acc[4] = {};
    float lsum[4] = {};

    uint4 ra = *reinterpret_cast<const uint4*>(Kb + (size_t)sr * D_MODEL + sc);
    uint4 rb = *reinterpret_cast<const uint4*>(Kb + (size_t)(sr + 32) * D_MODEL + sc);
    uint4 rc = *reinterpret_cast<const uint4*>(Vb + (size_t)sr * SEQ + sc);
    uint4 rd = *reinterpret_cast<const uint4*>(Vb + (size_t)(sr + 32) * SEQ + sc);

    for (int kt = 0; kt < ntiles; kt++) {
      const int kv0 = kt * 64;
      __syncthreads();
      *reinterpret_cast<uint4*>(&Ks[sr * 72 + sc]) = ra;
      *reinterpret_cast<uint4*>(&Ks[(sr + 32) * 72 + sc]) = rb;
      *reinterpret_cast<uint4*>(&Vs[sr * 72 + sc]) = rc;
      *reinterpret_cast<uint4*>(&Vs[(sr + 32) * 72 + sc]) = rd;
      __syncthreads();
      if (kt + 1 < ntiles) {
        const int kv1 = kv0 + 64;
        ra = *reinterpret_cast<const uint4*>(Kb + (size_t)(kv1 + sr) * D_MODEL + sc);
        rb = *reinterpret_cast<const uint4*>(Kb + (size_t)(kv1 + sr + 32) * D_MODEL + sc);
        rc = *reinterpret_cast<const uint4*>(Vb + (size_t)sr * SEQ + kv1 + sc);
        rd = *reinterpret_cast<const uint4*>(Vb + (size_t)(sr + 32) * SEQ + kv1 + sc);
      }

      // ---- QK^T over 64 kv cols ----
      f32x4 sAcc[4] = {};
#pragma unroll
      for (int kk = 0; kk < 2; kk++) {
        bf16x8 kf[4];
#pragma unroll
        for (int j = 0; j < 4; j++)
          kf[j] = __builtin_bit_cast(
              bf16x8, *reinterpret_cast<const short8*>(&Ks[(j * 16 + lr) * 72 + kk * 32 + quad * 8]));
#pragma unroll
        for (int j = 0; j < 4; j++)
          sAcc[j] = __builtin_amdgcn_mfma_f32_16x16x32_bf16(qf[kk], kf[j], sAcc[j], 0, 0, 0);
      }

      asm volatile("s_waitcnt lgkmcnt(0)" ::: "memory");  // prev P-frag reads drained
#pragma unroll
      for (int r = 0; r < 4; r++) {
        const int qpos = m0 + quad * 4 + r;
        float e[4];
#pragma unroll
        for (int j = 0; j < 4; j++) e[j] = EXP2F(sAcc[j][r]);
        if (kt == ntiles - 1) {
#pragma unroll
          for (int j = 0; j < 4; j++)
            if (kv0 + j * 16 + lr > qpos) e[j] = 0.f;
        }
        lsum[r] += (e[0] + e[1]) + (e[2] + e[3]);
        unsigned short* pr = &pw[(quad * 4 + r) * 72];
#pragma unroll
        for (int j = 0; j < 4; j++) pr[j * 16 + lr] = f2bf_rne(e[j]);
      }
      asm volatile("s_waitcnt lgkmcnt(0)" ::: "memory");  // P writes visible (wave-lockstep)

      // ---- PV ----
#pragma unroll
      for (int kk = 0; kk < 2; kk++) {
        bf16x8 pf = __builtin_bit_cast(
            bf16x8, *reinterpret_cast<const short8*>(&pw[lr * 72 + kk * 32 + quad * 8]));
#pragma unroll
        for (int c = 0; c < 4; c++) {
          bf16x8 vv = __builtin_bit_cast(
              bf16x8, *reinterpret_cast<const short8*>(&Vs[(c * 16 + lr) * 72 + kk * 32 + quad * 8]));
          o_acc[c] = __builtin_amdgcn_mfma_f32_16x16x32_bf16(pf, vv, o_acc[c], 0, 0, 0);
        }
      }
    }

    // epilogue
#pragma unroll
    for (int r = 0; r < 4; r++) {
      float l = lsum[r];
#pragma unroll
      for (int off = 1; off < 16; off <<= 1) l += __shfl_xor(l, off, 64);
      const float inv = 1.f / l;
      const int qpos = m0 + quad * 4 + r;
#pragma unroll
      for (int c = 0; c < 4; c++)
        O[base + (size_t)qpos * D_MODEL + c * 16 + lr] = f2bf_rne(o_acc[c][r] * inv);
    }
  }
}

// ---------------- launch ----------------
extern "C" void kernel_launch(void* const* d_in, const int* in_sizes, int n_in,
                              void* d_out, int out_size, void* d_ws, size_t ws_size,
                              hipStream_t stream) {
  const float* x  = (const float*)d_in[0];
  const float* Wq = (const float*)d_in[1];
  const float* Wk = (const float*)d_in[2];
  const float* Wv = (const float*)d_in[3];
  const float* Wo = (const float*)d_in[4];
  float* out = (float*)d_out;

  char* ws = (char*)d_ws;
  const size_t SZ_X = (size_t)M_ROWS * D_MODEL * 2;   // 16 MB
  const size_t SZ_W = (size_t)D_MODEL * D_MODEL * 2;  //  2 MB
  unsigned short* xb  = (unsigned short*)(ws);
  unsigned short* wqb = (unsigned short*)(ws + SZ_X);
  unsigned short* wkb = (unsigned short*)(ws + SZ_X + 1 * SZ_W);
  unsigned short* wvb = (unsigned short*)(ws + SZ_X + 2 * SZ_W);
  unsigned short* wob = (unsigned short*)(ws + SZ_X + 3 * SZ_W);
  unsigned short* Qb  = (unsigned short*)(ws + 1 * SZ_X + 4 * SZ_W);
  unsigned short* Kb  = (unsigned short*)(ws + 2 * SZ_X + 4 * SZ_W);
  unsigned short* Vt  = (unsigned short*)(ws + 3 * SZ_X + 4 * SZ_W);
  unsigned short* Ob  = xb;  // x dead after QKV projection

  cvt_all<<<12288, 256, 0, stream>>>(x, Wq, Wk, Wv, Wo, xb, wqb, wkb, wvb, wob);

  qkv_gemm<<<dim3(24, 64), 256, 0, stream>>>(xb, wqb, wkb, wvb, Qb, Kb, Vt);

  attn_causal<<<1024, 256, 0, stream>>>(Qb, Kb, Vt, Ob);

  gemm_bt_f32<<<dim3(8, 64), 256, 0, stream>>>(Ob, wob, out, M_ROWS, D_MODEL, D_MODEL);
}

// Round 8
// 265.363 us; speedup vs baseline: 1.1754x; 1.0418x over previous
//
#include <hip/hip_runtime.h>
#include <hip/hip_bf16.h>

#define D_MODEL 1024
#define N_HEADS 16
#define HEAD_DIM 64
#define BATCH 4
#define SEQ 2048
#define M_ROWS (BATCH * SEQ)  // 8192

typedef __attribute__((ext_vector_type(8))) __bf16 bf16x8;
typedef __attribute__((ext_vector_type(8))) short short8;
typedef __attribute__((ext_vector_type(4))) float f32x4;

static __device__ __forceinline__ unsigned short f2bf_rne(float f) {
  unsigned int u = __float_as_uint(f);
  u += 0x7FFFu + ((u >> 16) & 1u);
  return (unsigned short)(u >> 16);
}

#if __has_builtin(__builtin_amdgcn_exp2f)
#define EXP2F(x) __builtin_amdgcn_exp2f(x)
#else
#define EXP2F(x) exp2f(x)
#endif

static __device__ __forceinline__ void gl_lds16(const unsigned short* g, unsigned short* l) {
  __builtin_amdgcn_global_load_lds((const __attribute__((address_space(1))) unsigned int*)g,
                                   (__attribute__((address_space(3))) unsigned int*)l, 16, 0, 0);
}

// ---------------- merged fp32 -> bf16 conversion (x + 4 weights), one launch ----------------
__global__ __launch_bounds__(256) void cvt_all(const float* __restrict__ x,
                                               const float* __restrict__ wq,
                                               const float* __restrict__ wk,
                                               const float* __restrict__ wv,
                                               const float* __restrict__ wo,
                                               unsigned short* __restrict__ xb,
                                               unsigned short* __restrict__ wqb,
                                               unsigned short* __restrict__ wkb,
                                               unsigned short* __restrict__ wvb,
                                               unsigned short* __restrict__ wob) {
  const int bid = blockIdx.x;
  const float* src;
  unsigned short* dst;
  int i;
  if (bid < 8192) {
    src = x; dst = xb; i = bid * 256 + threadIdx.x;
  } else {
    int r = bid - 8192;
    int w = r >> 10;
    i = (r & 1023) * 256 + threadIdx.x;
    switch (w) {
      case 0: src = wq; dst = wqb; break;
      case 1: src = wk; dst = wkb; break;
      case 2: src = wv; dst = wvb; break;
      default: src = wo; dst = wob; break;
    }
  }
  float4 f = reinterpret_cast<const float4*>(src)[i];
  ushort4 o;
  o.x = f2bf_rne(f.x); o.y = f2bf_rne(f.y); o.z = f2bf_rne(f.z); o.w = f2bf_rne(f.w);
  reinterpret_cast<ushort4*>(dst)[i] = o;
}

// ---------------- fused QKV GEMM, double-buffered LDS (unchanged from round 7) ----------------
__global__ __launch_bounds__(256) void qkv_gemm(const unsigned short* __restrict__ A,
                                                const unsigned short* __restrict__ Wq,
                                                const unsigned short* __restrict__ Wk,
                                                const unsigned short* __restrict__ Wv,
                                                unsigned short* __restrict__ Qo,
                                                unsigned short* __restrict__ Ko,
                                                unsigned short* __restrict__ Vt) {
  __shared__ __align__(16) unsigned short smem[16384];  // As0 Bs0 As1 Bs1, 4096 shorts each
  const int t = threadIdx.x;
  const int widx = blockIdx.x >> 3;
  const int bn = blockIdx.x & 7, bm = blockIdx.y;
  const unsigned short* Bw = (widx == 0) ? Wq : (widx == 1) ? Wk : Wv;
  const float oscale = (widx == 0) ? 0.18033688f : 1.0f;  // Q: 1/8 * log2(e)
  const int K = D_MODEL, N = D_MODEL;

  const int wave = t >> 6, lane = t & 63;
  const int wm = (wave >> 1) * 64, wn = (wave & 1) * 64;
  const int lr = lane & 15, quad = lane >> 4;

  const int g0 = wave * 128 + lane, g1 = g0 + 64;
  const int r0 = g0 >> 2, c0 = (g0 & 3) << 3;
  const int r1 = g1 >> 2, c1 = (g1 & 3) << 3;
  const unsigned short* Arow0 = A + (size_t)(bm * 128 + r0) * K + c0;
  const unsigned short* Arow1 = A + (size_t)(bm * 128 + r1) * K + c1;
  const unsigned short* Brow0 = Bw + (size_t)(bn * 128 + r0) * K + c0;
  const unsigned short* Brow1 = Bw + (size_t)(bn * 128 + r1) * K + c1;

  f32x4 acc[4][4] = {};

  gl_lds16(Arow0, &smem[g0 * 8]);
  gl_lds16(Arow1, &smem[g1 * 8]);
  gl_lds16(Brow0, &smem[4096 + g0 * 8]);
  gl_lds16(Brow1, &smem[4096 + g1 * 8]);
  __syncthreads();

  for (int it = 0; it < 32; it++) {
    const int cur = (it & 1) * 8192;
    if (it + 1 < 32) {
      const int nxt = 8192 - cur;
      const int k1 = (it + 1) * 32;
      gl_lds16(Arow0 + k1, &smem[nxt + g0 * 8]);
      gl_lds16(Arow1 + k1, &smem[nxt + g1 * 8]);
      gl_lds16(Brow0 + k1, &smem[nxt + 4096 + g0 * 8]);
      gl_lds16(Brow1 + k1, &smem[nxt + 4096 + g1 * 8]);
    }
    const unsigned short* As = &smem[cur];
    const unsigned short* Bs = &smem[cur + 4096];

    bf16x8 af[4], bfr[4];
#pragma unroll
    for (int mt = 0; mt < 4; mt++)
      af[mt] = __builtin_bit_cast(
          bf16x8, *reinterpret_cast<const short8*>(&As[(wm + mt * 16 + lr) * 32 + quad * 8]));
#pragma unroll
    for (int nt = 0; nt < 4; nt++)
      bfr[nt] = __builtin_bit_cast(
          bf16x8, *reinterpret_cast<const short8*>(&Bs[(wn + nt * 16 + lr) * 32 + quad * 8]));
#pragma unroll
    for (int mt = 0; mt < 4; mt++)
#pragma unroll
      for (int nt = 0; nt < 4; nt++)
        acc[mt][nt] = __builtin_amdgcn_mfma_f32_16x16x32_bf16(af[mt], bfr[nt], acc[mt][nt], 0, 0, 0);
    __syncthreads();
  }

  if (widx < 2) {
    unsigned short* Cp = (widx == 0) ? Qo : Ko;
#pragma unroll
    for (int mt = 0; mt < 4; mt++) {
#pragma unroll
      for (int nt = 0; nt < 4; nt++) {
        int col = bn * 128 + wn + nt * 16 + lr;
#pragma unroll
        for (int r = 0; r < 4; r++) {
          int row = bm * 128 + wm + mt * 16 + quad * 4 + r;
          Cp[(size_t)row * N + col] = f2bf_rne(acc[mt][nt][r] * oscale);
        }
      }
    }
  } else {
    // V: transpose through LDS (reuses smem), write Vt[(b*16+h2)*64+d][s]
    const int b = bm >> 4;
    const int s0 = (bm & 15) * 128;
#pragma unroll
    for (int half = 0; half < 2; half++) {
      __syncthreads();
      if ((wave & 1) == half) {
#pragma unroll
        for (int nt = 0; nt < 4; nt++) {
#pragma unroll
          for (int mt = 0; mt < 4; mt++) {
#pragma unroll
            for (int r = 0; r < 4; r++) {
              int cl = nt * 16 + lr;                 // d within this 64-col half
              int rl = wm + mt * 16 + quad * 4 + r;  // s within 128-row tile
              smem[cl * 136 + rl] = f2bf_rne(acc[mt][nt][r]);
            }
          }
        }
      }
      __syncthreads();
      const int h2 = bn * 2 + half;
      const size_t rowbase = ((size_t)(b * N_HEADS + h2)) * HEAD_DIM;
#pragma unroll
      for (int i = 0; i < 4; i++) {
        int c = i * 256 + t;
        int d = c >> 4, s8 = (c & 15) * 8;
        uint4 v = *reinterpret_cast<const uint4*>(&smem[d * 136 + s8]);
        *reinterpret_cast<uint4*>(Vt + (rowbase + d) * SEQ + s0 + s8) = v;
      }
    }
  }
}

// ---------------- O-projection GEMM, 128x64 tiles, double-buffered, f32 out ----------------
// grid (16, 64) = 1024 blocks -> 4 resident blocks/CU. 4 waves in 2x2; wave = 64x32.
__global__ __launch_bounds__(256) void gemm_bt_f32(const unsigned short* __restrict__ A,
                                                   const unsigned short* __restrict__ Bw,
                                                   float* __restrict__ Cp,
                                                   int M, int N, int K) {
  __shared__ __align__(16) unsigned short smem[12288];  // A0[4096] B0[2048] A1 B1
  const int t = threadIdx.x;
  const int bn = blockIdx.x, bm = blockIdx.y;
  const int wave = t >> 6, lane = t & 63;
  const int wm = (wave >> 1) * 64, wn = (wave & 1) * 32;
  const int lr = lane & 15, quad = lane >> 4;

  // staging: A granules t, t+256 (of 512); B granule t (of 256)
  const int g0 = t, g1 = t + 256;
  const int ar0 = g0 >> 2, ac0 = (g0 & 3) << 3;
  const int ar1 = g1 >> 2, ac1 = (g1 & 3) << 3;
  const int br = t >> 2, bc = (t & 3) << 3;
  const unsigned short* Arow0 = A + (size_t)(bm * 128 + ar0) * K + ac0;
  const unsigned short* Arow1 = A + (size_t)(bm * 128 + ar1) * K + ac1;
  const unsigned short* Brow = Bw + (size_t)(bn * 64 + br) * K + bc;

  f32x4 acc[4][2] = {};

  gl_lds16(Arow0, &smem[g0 * 8]);
  gl_lds16(Arow1, &smem[g1 * 8]);
  gl_lds16(Brow, &smem[4096 + t * 8]);
  __syncthreads();

  const int niter = K / 32;
  for (int it = 0; it < niter; it++) {
    const int cur = (it & 1) * 6144;
    if (it + 1 < niter) {
      const int nxt = 6144 - cur;
      const int k1 = (it + 1) * 32;
      gl_lds16(Arow0 + k1, &smem[nxt + g0 * 8]);
      gl_lds16(Arow1 + k1, &smem[nxt + g1 * 8]);
      gl_lds16(Brow + k1, &smem[nxt + 4096 + t * 8]);
    }
    const unsigned short* As = &smem[cur];
    const unsigned short* Bs = &smem[cur + 4096];

    bf16x8 af[4], bfr[2];
#pragma unroll
    for (int mt = 0; mt < 4; mt++)
      af[mt] = __builtin_bit_cast(
          bf16x8, *reinterpret_cast<const short8*>(&As[(wm + mt * 16 + lr) * 32 + quad * 8]));
#pragma unroll
    for (int nt = 0; nt < 2; nt++)
      bfr[nt] = __builtin_bit_cast(
          bf16x8, *reinterpret_cast<const short8*>(&Bs[(wn + nt * 16 + lr) * 32 + quad * 8]));
#pragma unroll
    for (int mt = 0; mt < 4; mt++)
#pragma unroll
      for (int nt = 0; nt < 2; nt++)
        acc[mt][nt] = __builtin_amdgcn_mfma_f32_16x16x32_bf16(af[mt], bfr[nt], acc[mt][nt], 0, 0, 0);
    __syncthreads();
  }

#pragma unroll
  for (int mt = 0; mt < 4; mt++) {
#pragma unroll
    for (int nt = 0; nt < 2; nt++) {
      int col = bn * 64 + wn + nt * 16 + lr;
#pragma unroll
      for (int r = 0; r < 4; r++) {
        int row = bm * 128 + wm + mt * 16 + quad * 4 + r;
        Cp[(size_t)row * N + col] = acc[mt][nt][r];
      }
    }
  }
}

// ---------------- causal flash attention v6: 128-row q-tiles, 512-thread blocks ----------------
// 512 blocks, (b,h,p): p=0..7 -> q-tiles {p, 15-p} (128 rows each), two phases -> exactly
// 34 kv-tiles per block (uniform). 8 waves x 16 q rows. KV tiles of 64 staged block-
// cooperatively (1 K + 1 V granule per thread); register prefetch. Fixed-max softmax
// base-2 (Q pre-scaled by log2(e)/8). Halves K/V staging traffic vs 64-row version.
__global__ __launch_bounds__(512, 4) void attn_causal(const unsigned short* __restrict__ Q,
                                                      const unsigned short* __restrict__ Km,
                                                      const unsigned short* __restrict__ Vt,
                                                      unsigned short* __restrict__ O) {
  __shared__ __align__(16) unsigned short Ks[64 * 72];
  __shared__ __align__(16) unsigned short Vs[64 * 72];
  __shared__ __align__(16) unsigned short Ps[8][16 * 72];

  const int bid = blockIdx.x;
  const int p = bid & 7;
  const int h = (bid >> 3) & 15;
  const int b = bid >> 7;

  const int t = threadIdx.x;
  const int wave = t >> 6, lane = t & 63;
  const int lr = lane & 15, quad = lane >> 4;

  const size_t base = (size_t)b * SEQ * D_MODEL + h * HEAD_DIM;
  const unsigned short* Qb = Q + base;
  const unsigned short* Kb = Km + base;
  const unsigned short* Vb = Vt + (size_t)(b * N_HEADS + h) * HEAD_DIM * SEQ;
  unsigned short* pw = &Ps[wave][0];

  const int sr = t >> 3, sc = (t & 7) << 3;  // staging: row sr (0..63), col sc (8 shorts)

  for (int ph = 0; ph < 2; ph++) {
    const int qt = ph ? (15 - p) : p;
    const int m0 = qt * 128 + wave * 16;
    const int ntiles = (qt + 1) * 2;

    bf16x8 qf[2];
#pragma unroll
    for (int kk = 0; kk < 2; kk++)
      qf[kk] = __builtin_bit_cast(
          bf16x8,
          *reinterpret_cast<const short8*>(Qb + (size_t)(m0 + lr) * D_MODEL + kk * 32 + quad * 8));

    f32x4 o_acc[4] = {};
    float lsum[4] = {};

    uint4 ra = *reinterpret_cast<const uint4*>(Kb + (size_t)sr * D_MODEL + sc);
    uint4 rc = *reinterpret_cast<const uint4*>(Vb + (size_t)sr * SEQ + sc);

    for (int kt = 0; kt < ntiles; kt++) {
      const int kv0 = kt * 64;
      __syncthreads();  // all waves done reading prior tile (and prior phase)
      *reinterpret_cast<uint4*>(&Ks[sr * 72 + sc]) = ra;
      *reinterpret_cast<uint4*>(&Vs[sr * 72 + sc]) = rc;
      __syncthreads();
      if (kt + 1 < ntiles) {  // prefetch next tile (overlaps compute)
        const int kv1 = kv0 + 64;
        ra = *reinterpret_cast<const uint4*>(Kb + (size_t)(kv1 + sr) * D_MODEL + sc);
        rc = *reinterpret_cast<const uint4*>(Vb + (size_t)sr * SEQ + kv1 + sc);
      }

      // ---- QK^T over 64 kv cols ----
      f32x4 sAcc[4] = {};
#pragma unroll
      for (int kk = 0; kk < 2; kk++) {
        bf16x8 kf[4];
#pragma unroll
        for (int j = 0; j < 4; j++)
          kf[j] = __builtin_bit_cast(
              bf16x8, *reinterpret_cast<const short8*>(&Ks[(j * 16 + lr) * 72 + kk * 32 + quad * 8]));
#pragma unroll
        for (int j = 0; j < 4; j++)
          sAcc[j] = __builtin_amdgcn_mfma_f32_16x16x32_bf16(qf[kk], kf[j], sAcc[j], 0, 0, 0);
      }

      asm volatile("s_waitcnt lgkmcnt(0)" ::: "memory");  // prev P-frag reads drained
      const bool needmask = (kv0 + 63 > m0);              // wave-uniform
#pragma unroll
      for (int r = 0; r < 4; r++) {
        const int qpos = m0 + quad * 4 + r;
        float e[4];
#pragma unroll
        for (int j = 0; j < 4; j++) e[j] = EXP2F(sAcc[j][r]);
        if (needmask) {
#pragma unroll
          for (int j = 0; j < 4; j++)
            if (kv0 + j * 16 + lr > qpos) e[j] = 0.f;
        }
        lsum[r] += (e[0] + e[1]) + (e[2] + e[3]);
        unsigned short* pr = &pw[(quad * 4 + r) * 72];
#pragma unroll
        for (int j = 0; j < 4; j++) pr[j * 16 + lr] = f2bf_rne(e[j]);
      }
      asm volatile("s_waitcnt lgkmcnt(0)" ::: "memory");  // P writes visible (wave-lockstep)

      // ---- PV ----
#pragma unroll
      for (int kk = 0; kk < 2; kk++) {
        bf16x8 pf = __builtin_bit_cast(
            bf16x8, *reinterpret_cast<const short8*>(&pw[lr * 72 + kk * 32 + quad * 8]));
#pragma unroll
        for (int c = 0; c < 4; c++) {
          bf16x8 vv = __builtin_bit_cast(
              bf16x8, *reinterpret_cast<const short8*>(&Vs[(c * 16 + lr) * 72 + kk * 32 + quad * 8]));
          o_acc[c] = __builtin_amdgcn_mfma_f32_16x16x32_bf16(pf, vv, o_acc[c], 0, 0, 0);
        }
      }
    }

    // epilogue
#pragma unroll
    for (int r = 0; r < 4; r++) {
      float l = lsum[r];
#pragma unroll
      for (int off = 1; off < 16; off <<= 1) l += __shfl_xor(l, off, 64);
      const float inv = 1.f / l;
      const int qpos = m0 + quad * 4 + r;
#pragma unroll
      for (int c = 0; c < 4; c++)
        O[base + (size_t)qpos * D_MODEL + c * 16 + lr] = f2bf_rne(o_acc[c][r] * inv);
    }
  }
}

// ---------------- launch ----------------
extern "C" void kernel_launch(void* const* d_in, const int* in_sizes, int n_in,
                              void* d_out, int out_size, void* d_ws, size_t ws_size,
                              hipStream_t stream) {
  const float* x  = (const float*)d_in[0];
  const float* Wq = (const float*)d_in[1];
  const float* Wk = (const float*)d_in[2];
  const float* Wv = (const float*)d_in[3];
  const float* Wo = (const float*)d_in[4];
  float* out = (float*)d_out;

  char* ws = (char*)d_ws;
  const size_t SZ_X = (size_t)M_ROWS * D_MODEL * 2;   // 16 MB
  const size_t SZ_W = (size_t)D_MODEL * D_MODEL * 2;  //  2 MB
  unsigned short* xb  = (unsigned short*)(ws);
  unsigned short* wqb = (unsigned short*)(ws + SZ_X);
  unsigned short* wkb = (unsigned short*)(ws + SZ_X + 1 * SZ_W);
  unsigned short* wvb = (unsigned short*)(ws + SZ_X + 2 * SZ_W);
  unsigned short* wob = (unsigned short*)(ws + SZ_X + 3 * SZ_W);
  unsigned short* Qb  = (unsigned short*)(ws + 1 * SZ_X + 4 * SZ_W);
  unsigned short* Kb  = (unsigned short*)(ws + 2 * SZ_X + 4 * SZ_W);
  unsigned short* Vt  = (unsigned short*)(ws + 3 * SZ_X + 4 * SZ_W);
  unsigned short* Ob  = xb;  // x dead after QKV projection

  cvt_all<<<12288, 256, 0, stream>>>(x, Wq, Wk, Wv, Wo, xb, wqb, wkb, wvb, wob);

  qkv_gemm<<<dim3(24, 64), 256, 0, stream>>>(xb, wqb, wkb, wvb, Qb, Kb, Vt);

  attn_causal<<<512, 512, 0, stream>>>(Qb, Kb, Vt, Ob);

  gemm_bt_f32<<<dim3(16, 64), 256, 0, stream>>>(Ob, wob, out, M_ROWS, D_MODEL, D_MODEL);
}